// Round 1
// baseline (277.257 us; speedup 1.0000x reference)
//
#include <hip/hip_runtime.h>

// Butterfly network: 12 stages over rows of 4096 fp32.
// y[p] <- W[s][p][0]*y[p] + W[s][p][1]*y[p^d],  d = 1<<s, s = 0..11
//
// One block (256 thr) processes RPB=4 rows entirely on-chip:
//   layout 1 (p = 16t+i)            -> stages 0..3 in registers
//   layout 2 (p = hi*256 + 16j+lo)  -> stages 4..7 in registers
//   layout 3 (p = 256k + t)         -> stages 8..11 in registers, coalesced store
// Layout swaps go through 64 KB LDS with XOR swizzle sig(p)=p^((p>>5)&31)
// (all four LDS patterns are <=2-way bank aliased => conflict-free).

constexpr int LROW = 4096;
constexpr int RPB  = 4;     // rows per block
constexpr int NBLK = 8192 / RPB;

__device__ __forceinline__ int sig(int p) { return p ^ ((p >> 5) & 31); }

__global__ __launch_bounds__(256, 2)
void butterfly12_kernel(const float* __restrict__ x,
                        const float* __restrict__ W,
                        float* __restrict__ out)
{
    __shared__ float lds[RPB * LROW];   // 64 KB -> 2 blocks/CU

    const int t    = threadIdx.x;
    const int hi   = t >> 4;
    const int lo   = t & 15;
    const int row0 = blockIdx.x * RPB;

    float v[RPB][16];

    // ---- load: layout 1, p = 16t + i, 4 x float4 per row ----
    #pragma unroll
    for (int r = 0; r < RPB; ++r) {
        const float4* xr = reinterpret_cast<const float4*>(x + (size_t)(row0 + r) * LROW);
        #pragma unroll
        for (int m = 0; m < 4; ++m) {
            const float4 q = xr[t * 4 + m];
            v[r][4*m+0] = q.x; v[r][4*m+1] = q.y;
            v[r][4*m+2] = q.z; v[r][4*m+3] = q.w;
        }
    }

    // ---- phase 1: stages 0..3, p = 16t + i ----
    #pragma unroll
    for (int b = 0; b < 4; ++b) {
        const int s = b;
        float2 ws[16];
        const float4* wq = reinterpret_cast<const float4*>(W + ((size_t)s * LROW + t * 16) * 2);
        #pragma unroll
        for (int m = 0; m < 8; ++m) {
            const float4 q = wq[m];
            ws[2*m]   = make_float2(q.x, q.y);
            ws[2*m+1] = make_float2(q.z, q.w);
        }
        const int dl = 1 << b;
        #pragma unroll
        for (int g = 0; g < 16; g += 2*dl)
            #pragma unroll
            for (int m = 0; m < dl; ++m) {
                const int a = g + m, c = a + dl;
                #pragma unroll
                for (int r = 0; r < RPB; ++r) {
                    const float va = v[r][a], vb = v[r][c];
                    v[r][a] = ws[a].x * va + ws[a].y * vb;
                    v[r][c] = ws[c].x * vb + ws[c].y * va;
                }
            }
    }

    // ---- transition 1 -> layout 2 (p = hi*256 + 16j + lo) ----
    #pragma unroll
    for (int r = 0; r < RPB; ++r)
        #pragma unroll
        for (int i = 0; i < 16; ++i)
            lds[r * LROW + sig(16*t + i)] = v[r][i];
    __syncthreads();
    #pragma unroll
    for (int r = 0; r < RPB; ++r)
        #pragma unroll
        for (int j = 0; j < 16; ++j)
            v[r][j] = lds[r * LROW + sig(hi*256 + j*16 + lo)];

    // ---- phase 2: stages 4..7, p = hi*256 + 16j + lo ----
    #pragma unroll
    for (int b = 0; b < 4; ++b) {
        const int s = 4 + b;
        float2 ws[16];
        #pragma unroll
        for (int j = 0; j < 16; ++j)
            ws[j] = *reinterpret_cast<const float2*>(W + ((size_t)s * LROW + hi*256 + j*16 + lo) * 2);
        const int dl = 1 << b;
        #pragma unroll
        for (int g = 0; g < 16; g += 2*dl)
            #pragma unroll
            for (int m = 0; m < dl; ++m) {
                const int a = g + m, c = a + dl;
                #pragma unroll
                for (int r = 0; r < RPB; ++r) {
                    const float va = v[r][a], vb = v[r][c];
                    v[r][a] = ws[a].x * va + ws[a].y * vb;
                    v[r][c] = ws[c].x * vb + ws[c].y * va;
                }
            }
    }

    // ---- transition 2 -> layout 3 (p = 256k + t) ----
    // write back to the exact addresses this thread read in transition 1
    // (thread-private set => no barrier needed before the writes)
    #pragma unroll
    for (int r = 0; r < RPB; ++r)
        #pragma unroll
        for (int j = 0; j < 16; ++j)
            lds[r * LROW + sig(hi*256 + j*16 + lo)] = v[r][j];
    __syncthreads();
    #pragma unroll
    for (int r = 0; r < RPB; ++r)
        #pragma unroll
        for (int k = 0; k < 16; ++k)
            v[r][k] = lds[r * LROW + sig(k*256 + t)];

    // ---- phase 3: stages 8..11, p = 256k + t ----
    #pragma unroll
    for (int b = 0; b < 4; ++b) {
        const int s = 8 + b;
        float2 ws[16];
        #pragma unroll
        for (int k = 0; k < 16; ++k)
            ws[k] = *reinterpret_cast<const float2*>(W + ((size_t)s * LROW + k*256 + t) * 2);
        const int dl = 1 << b;
        #pragma unroll
        for (int g = 0; g < 16; g += 2*dl)
            #pragma unroll
            for (int m = 0; m < dl; ++m) {
                const int a = g + m, c = a + dl;
                #pragma unroll
                for (int r = 0; r < RPB; ++r) {
                    const float va = v[r][a], vb = v[r][c];
                    v[r][a] = ws[a].x * va + ws[a].y * vb;
                    v[r][c] = ws[c].x * vb + ws[c].y * va;
                }
            }
    }

    // ---- store: layout 3 => lane-consecutive dword stores, fully coalesced ----
    #pragma unroll
    for (int r = 0; r < RPB; ++r) {
        float* orow = out + (size_t)(row0 + r) * LROW;
        #pragma unroll
        for (int k = 0; k < 16; ++k)
            orow[k*256 + t] = v[r][k];
    }
}

extern "C" void kernel_launch(void* const* d_in, const int* in_sizes, int n_in,
                              void* d_out, int out_size, void* d_ws, size_t ws_size,
                              hipStream_t stream) {
    const float* x = (const float*)d_in[0];   // (8192, 4096) fp32
    const float* W = (const float*)d_in[1];   // (12, 4096, 2) fp32
    float* out = (float*)d_out;               // (8192, 4096) fp32

    butterfly12_kernel<<<NBLK, 256, 0, stream>>>(x, W, out);
}